// Round 18
// baseline (479.986 us; speedup 1.0000x reference)
//
#include <hip/hip_runtime.h>
#include <hip/hip_bf16.h>

#define NPTS 2048
#define KNN 80
#define KSEL 81
#define BATCH 4

__device__ __forceinline__ unsigned f2key(float f) {
    unsigned u = __float_as_uint(f);
    return u ^ ((u & 0x80000000u) ? 0xFFFFFFFFu : 0x80000000u);
}
__device__ __forceinline__ float key2f(unsigned k) {
    unsigned u = (k & 0x80000000u) ? (k ^ 0x80000000u) : ~k;
    return __uint_as_float(u);
}

// ---------------- xx (fp64) ----------------
__global__ void xx64_kernel(const float* __restrict__ x, long sb, int C, double* __restrict__ xx) {
    int i = blockIdx.x * 256 + threadIdx.x;
    if (i >= BATCH * NPTS) return;
    int b = i / NPTS, n = i % NPTS;
    const float* xp = x + (long)b * sb + n;
    double s = 0.0;
    for (int c = 0; c < C; ++c) { double v = (double)xp[(long)c * NPTS]; s = fma(v, v, s); }
    xx[i] = s;
}

// ---------------- dist: fp32 accumulate, fp64 final combine -> fp32 ----------------
__global__ __launch_bounds__(256) void dist_kernel(
    const float* __restrict__ x, long sb, int C,
    const double* __restrict__ xx, float* __restrict__ dist, int b_base) {
    int bz = blockIdx.z;
    int b = b_base + bz;
    int i0 = blockIdx.y * 64, j0 = blockIdx.x * 64;
    __shared__ float xi[32][64];
    __shared__ float xj[32][64];
    const float* xb = x + (long)b * sb;
    int tid = threadIdx.x, tx = tid & 15, ty = tid >> 4;
    float acc[4][4] = {};
    for (int cc = 0; cc < C; cc += 32) {
        int Cc = C - cc; if (Cc > 32) Cc = 32;
        for (int t = tid; t < Cc * 64; t += 256) {
            int c = t >> 6, l = t & 63;
            xi[c][l] = xb[(long)(cc + c) * NPTS + i0 + l];
            xj[c][l] = xb[(long)(cc + c) * NPTS + j0 + l];
        }
        __syncthreads();
        for (int c = 0; c < Cc; ++c) {
            float a[4], bb[4];
#pragma unroll
            for (int u = 0; u < 4; ++u) a[u] = xi[c][ty * 4 + u];
#pragma unroll
            for (int v = 0; v < 4; ++v) bb[v] = xj[c][tx * 4 + v];
#pragma unroll
            for (int u = 0; u < 4; ++u)
#pragma unroll
                for (int v = 0; v < 4; ++v) acc[u][v] = fmaf(a[u], bb[v], acc[u][v]);
        }
        __syncthreads();
    }
    const double* xxb = xx + b * NPTS;
    float* drow = dist + (long)bz * NPTS * NPTS;
#pragma unroll
    for (int u = 0; u < 4; ++u) {
        int i = i0 + ty * 4 + u;
        double xxi = xxb[i];
#pragma unroll
        for (int v = 0; v < 4; ++v) {
            int j = j0 + tx * 4 + v;
            drow[(long)i * NPTS + j] = (float)(2.0 * (double)acc[u][v] - xxi - xxb[j]);
        }
    }
}

// ---------------- top-81: wave-per-row radix select, 4-copy histogram ----------------
__global__ __launch_bounds__(256) void topk_wave_kernel(
    const float* __restrict__ dist, int* __restrict__ idxout,
    int* __restrict__ flags, int b_base) {
    int bz = blockIdx.z;
    int b = b_base + bz;
    int tid = threadIdx.x;
    int lane = tid & 63, w = tid >> 6;
    int row = blockIdx.x * 4 + w;
    const float* dr = dist + ((long)bz * NPTS + row) * NPTS;

    unsigned kv[32];
#pragma unroll
    for (int i = 0; i < 8; ++i) {
        float4 a = *(const float4*)(dr + i * 256 + lane * 4);
        kv[i * 4 + 0] = f2key(a.x);
        kv[i * 4 + 1] = f2key(a.y);
        kv[i * 4 + 2] = f2key(a.z);
        kv[i * 4 + 3] = f2key(a.w);
    }

    __shared__ unsigned hist[4][256][4];   // [wave][bin][copy]
    __shared__ int sel_s[4][KSEL];
    __shared__ float selv_s[4][KSEL];

    unsigned prefix = 0;
    int rem = KSEL;
    int cp = lane & 3;

    for (int pass = 0; pass < 4; ++pass) {
        int shift = 24 - pass * 8;
        uint4* h4 = (uint4*)&hist[w][0][0];
#pragma unroll
        for (int t = 0; t < 4; ++t) h4[lane + t * 64] = make_uint4(0u, 0u, 0u, 0u);
        unsigned pm = (pass == 0) ? 0u : (0xFFFFFFFFu << (shift + 8));
#pragma unroll
        for (int u = 0; u < 32; ++u) {
            if ((kv[u] & pm) == prefix)
                atomicAdd(&hist[w][(kv[u] >> shift) & 255u][cp], 1u);
        }
        uint4 c0 = h4[lane * 4 + 0];
        uint4 c1 = h4[lane * 4 + 1];
        uint4 c2 = h4[lane * 4 + 2];
        uint4 c3 = h4[lane * 4 + 3];
        unsigned b0 = c0.x + c0.y + c0.z + c0.w;
        unsigned b1 = c1.x + c1.y + c1.z + c1.w;
        unsigned b2 = c2.x + c2.y + c2.z + c2.w;
        unsigned b3 = c3.x + c3.y + c3.z + c3.w;
        unsigned loc3 = b3, loc2 = b3 + b2, loc1 = b3 + b2 + b1, loc0 = b3 + b2 + b1 + b0;
        unsigned tot = loc0;
        unsigned suf = tot;
#pragma unroll
        for (int d = 1; d < 64; d <<= 1) {
            unsigned o = __shfl_down(suf, d);
            suf += (lane + d < 64) ? o : 0u;
        }
        unsigned after = suf - tot;
        int fdig = -1, frem = 0;
        unsigned ge, gt;
        ge = loc0 + after; gt = loc1 + after;
        if (ge >= (unsigned)rem && gt < (unsigned)rem) { fdig = lane * 4 + 0; frem = rem - (int)gt; }
        ge = loc1 + after; gt = loc2 + after;
        if (ge >= (unsigned)rem && gt < (unsigned)rem) { fdig = lane * 4 + 1; frem = rem - (int)gt; }
        ge = loc2 + after; gt = loc3 + after;
        if (ge >= (unsigned)rem && gt < (unsigned)rem) { fdig = lane * 4 + 2; frem = rem - (int)gt; }
        ge = loc3 + after; gt = after;
        if (ge >= (unsigned)rem && gt < (unsigned)rem) { fdig = lane * 4 + 3; frem = rem - (int)gt; }
        unsigned long long bal = __ballot(fdig >= 0);
        int src = __ffsll((unsigned long long)bal) - 1;
        fdig = __shfl(fdig, src);
        frem = __shfl(frem, src);
        prefix |= ((unsigned)fdig) << shift;
        rem = frem;
    }

    int myc = 0;
#pragma unroll
    for (int u = 0; u < 32; ++u) myc += (kv[u] > prefix) ? 1 : 0;
    int inc = myc;
#pragma unroll
    for (int d = 1; d < 64; d <<= 1) {
        int o = __shfl_up(inc, d);
        inc += (lane >= d) ? o : 0;
    }
    int off = inc - myc;
    int pos = off;
#pragma unroll
    for (int u = 0; u < 32; ++u) {
        if (kv[u] > prefix) {
            int e = (u >> 2) * 256 + lane * 4 + (u & 3);
            sel_s[w][pos] = e;
            selv_s[w][pos] = key2f(kv[u]);
            ++pos;
        }
    }
    int cgt = __shfl(inc, 63);

    unsigned tmask = 0;
#pragma unroll
    for (int u = 0; u < 32; ++u)
        if (kv[u] == prefix) tmask |= (1u << u);
    float vtie = key2f(prefix);
    for (int t = 0; t < rem; ++t) {
        int best = 0x7FFFFFFF;
        unsigned m = tmask;
        while (m) {
            int u = __ffs(m) - 1;
            m &= m - 1;
            int e = (u >> 2) * 256 + lane * 4 + (u & 3);
            best = min(best, e);
        }
#pragma unroll
        for (int d = 32; d > 0; d >>= 1) best = min(best, __shfl_xor(best, d));
        if (((best >> 2) & 63) == lane) {
            int u = ((best >> 8) << 2) | (best & 3);
            tmask &= ~(1u << u);
        }
        if (lane == 0) { sel_s[w][cgt + t] = best; selv_s[w][cgt + t] = vtie; }
    }

    unsigned bk = 0xFFFFFFFFu; int bi = -1, bp = -1;
    if (lane < KSEL) { bk = f2key(selv_s[w][lane]); bi = sel_s[w][lane]; bp = lane; }
    int l2 = lane + 64;
    if (l2 < KSEL) {
        unsigned k2 = f2key(selv_s[w][l2]); int i2 = sel_s[w][l2];
        if (k2 < bk || (k2 == bk && i2 > bi)) { bk = k2; bi = i2; bp = l2; }
    }
#pragma unroll
    for (int d = 32; d > 0; d >>= 1) {
        unsigned ok = __shfl_xor(bk, d);
        int oi = __shfl_xor(bi, d);
        int op = __shfl_xor(bp, d);
        if (ok < bk || (ok == bk && oi > bi)) { bk = ok; bi = oi; bp = op; }
    }
    int p81 = bp;
    bk = 0xFFFFFFFFu; bi = -1; bp = -1;
    if (lane < KSEL && lane != p81) { bk = f2key(selv_s[w][lane]); bi = sel_s[w][lane]; bp = lane; }
    if (l2 < KSEL && l2 != p81) {
        unsigned k2 = f2key(selv_s[w][l2]); int i2 = sel_s[w][l2];
        if (k2 < bk || (k2 == bk && i2 > bi)) { bk = k2; bi = i2; bp = l2; }
    }
#pragma unroll
    for (int d = 32; d > 0; d >>= 1) {
        unsigned ok = __shfl_xor(bk, d);
        int oi = __shfl_xor(bi, d);
        int op = __shfl_xor(bp, d);
        if (ok < bk || (ok == bk && oi > bi)) { bk = ok; bi = oi; bp = op; }
    }
    int p80 = bp;

    if (lane == 0) {
        int ts; float tv;
        ts = sel_s[w][80]; sel_s[w][80] = sel_s[w][p81]; sel_s[w][p81] = ts;
        tv = selv_s[w][80]; selv_s[w][80] = selv_s[w][p81]; selv_s[w][p81] = tv;
        if (p80 == 80) p80 = p81;
        ts = sel_s[w][79]; sel_s[w][79] = sel_s[w][p80]; sel_s[w][p80] = ts;
        tv = selv_s[w][79]; selv_s[w][79] = selv_s[w][p80]; selv_s[w][p80] = tv;
        float d80f = selv_s[w][79], d81f = selv_s[w][80];
        float eta = 8e-5f + 4e-6f * fabsf(d80f);
        flags[b * NPTS + row] = ((d80f - d81f) <= eta) ? 1 : 0;
    }
    int* outp = idxout + ((long)b * NPTS + row) * KSEL;
    for (int t = lane; t < KSEL; t += 64) outp[t] = sel_s[w][t];
}

// ---------------- p/r projections ----------------
template<int C, int O>
__global__ __launch_bounds__(256) void pr_kernel(
    const float* __restrict__ x, long sb, const float* __restrict__ W,
    float* __restrict__ p, float* __restrict__ r) {
    __shared__ float wp[C * O];
    __shared__ float wr[C * O];
    __shared__ float xs[C][32];
    int nb = NPTS / 32;
    int b = blockIdx.x / nb;
    int n0 = (blockIdx.x % nb) * 32;
    int tid = threadIdx.x;
    for (int t = tid; t < C * O; t += 256) {
        int o = t / C, c = t % C;
        float w1 = W[o * 2 * C + c];
        wp[o * C + c] = w1;
        wr[o * C + c] = W[o * 2 * C + C + c] - w1;
    }
    const float* xb = x + (long)b * sb;
    for (int t = tid; t < C * 32; t += 256) {
        int c = t / 32, nn = t & 31;
        xs[c][nn] = xb[(long)c * NPTS + n0 + nn];
    }
    __syncthreads();
    int o = tid % O;
    int nl0 = tid / O, per = 256 / O;
    for (int nl = nl0; nl < 32; nl += per) {
        float pa = 0.f, ra = 0.f;
        for (int c = 0; c < C; ++c) {
            float xv = xs[c][nl];
            pa = fmaf(wp[o * C + c], xv, pa);
            ra = fmaf(wr[o * C + c], xv, ra);
        }
        long po = ((long)b * NPTS + n0 + nl) * O + o;
        p[po] = pa;
        r[po] = ra;
    }
}

// ---------------- FUSED gather: hilo + fp64 stats via global atomics ----------------
template<int O, int NT>
__global__ __launch_bounds__(256) void gather_kernel(
    const float* __restrict__ p, const float* __restrict__ r,
    const int* __restrict__ idx, float4* __restrict__ hilo,
    double* __restrict__ stats) {
    const int R = (NT * O) / 256;
    const int STEP = 256 / O;
    __shared__ float r_s[NT * O];
    __shared__ int idx_s[NT * KSEL];
    __shared__ double gs8[8], gq8[8];
    int nb = NPTS / NT;
    int b = blockIdx.x / nb;
    int n0 = (blockIdx.x % nb) * NT;
    int tid = threadIdx.x;
    for (int t = tid; t < NT * O; t += 256) r_s[t] = r[((long)b * NPTS + n0) * O + t];
    for (int t = tid; t < NT * KSEL; t += 256) idx_s[t] = idx[((long)b * NPTS + n0) * KSEL + t];
    __syncthreads();
    int o = tid % O;
    int nlb = tid / O;
    const float* pb = p + (long)b * NPTS * O;
    float hi[R], lo[R], ha[R], hb[R], rv[R];
    int nlr[R];
#pragma unroll
    for (int u = 0; u < R; ++u) {
        nlr[u] = nlb + u * STEP;
        rv[u] = r_s[nlr[u] * O + o];
        hi[u] = -3.0e38f; lo[u] = 3.0e38f;
    }
    float s0 = 0.f, s1 = 0.f, q0 = 0.f, q1 = 0.f;
    int kk = 0;
    for (; kk + 3 < KNN - 1; kk += 4) {
        int j0[R], j1[R], j2[R], j3[R];
#pragma unroll
        for (int u = 0; u < R; ++u) {
            const int* ip = &idx_s[nlr[u] * KSEL + kk];
            j0[u] = ip[0]; j1[u] = ip[1]; j2[u] = ip[2]; j3[u] = ip[3];
        }
#pragma unroll
        for (int u = 0; u < R; ++u) {
            float h0 = pb[(long)j0[u] * O + o] + rv[u];
            float h1 = pb[(long)j1[u] * O + o] + rv[u];
            float h2 = pb[(long)j2[u] * O + o] + rv[u];
            float h3 = pb[(long)j3[u] * O + o] + rv[u];
            hi[u] = fmaxf(hi[u], fmaxf(fmaxf(h0, h1), fmaxf(h2, h3)));
            lo[u] = fminf(lo[u], fminf(fminf(h0, h1), fminf(h2, h3)));
            s0 += h0 + h2;
            s1 += h1 + h3;
            q0 = fmaf(h0, h0, q0); q0 = fmaf(h2, h2, q0);
            q1 = fmaf(h1, h1, q1); q1 = fmaf(h3, h3, q1);
        }
    }
    for (; kk < KNN - 1; ++kk) {
#pragma unroll
        for (int u = 0; u < R; ++u) {
            int j = idx_s[nlr[u] * KSEL + kk];
            float h = pb[(long)j * O + o] + rv[u];
            hi[u] = fmaxf(hi[u], h);
            lo[u] = fminf(lo[u], h);
            s0 += h;
            q0 = fmaf(h, h, q0);
        }
    }
#pragma unroll
    for (int u = 0; u < R; ++u) {
        int j = idx_s[nlr[u] * KSEL + (KNN - 1)];
        ha[u] = pb[(long)j * O + o] + rv[u];
        s0 += ha[u];
        q0 = fmaf(ha[u], ha[u], q0);
        int j2 = idx_s[nlr[u] * KSEL + KNN];
        hb[u] = pb[(long)j2 * O + o] + rv[u];
    }
#pragma unroll
    for (int u = 0; u < R; ++u)
        hilo[((long)b * NPTS + n0 + nlr[u]) * O + o] = make_float4(hi[u], lo[u], ha[u], hb[u]);
    double s = (double)s0 + (double)s1;
    double q = (double)q0 + (double)q1;
    for (int off = 16; off > 0; off >>= 1) {
        s += __shfl_xor(s, off);
        q += __shfl_xor(q, off);
    }
    int hw = tid >> 5;
    if ((tid & 31) == 0) { gs8[hw] = s; gq8[hw] = q; }
    __syncthreads();
    if (tid < 2) {
        double ss = 0.0, qq = 0.0;
        for (int h2 = 0; h2 < 8; ++h2) {
            int o0 = (h2 * 32) % O;
            int g = o0 / (O / 2);
            if (g == tid) { ss += gs8[h2]; qq += gq8[h2]; }
        }
        atomicAdd(&stats[(b * 2 + tid) * 2 + 0], ss);
        atomicAdd(&stats[(b * 2 + tid) * 2 + 1], qq);
    }
}

// ---------------- finalize: compute ms from stats + normalize extremes + leaky + hedge ----------------
template<int O>
__global__ __launch_bounds__(256) void finalize_kernel(
    const float4* __restrict__ hilo, const int* __restrict__ flags,
    const double* __restrict__ st, double M,
    const float* __restrict__ gamma, const float* __restrict__ beta,
    float* __restrict__ featP, float* __restrict__ featH, int coff) {
    const int NT = 16;
    __shared__ float smP[O * NT], smH[O * NT];
    __shared__ float sc_s[O], sh_s[O];
    __shared__ int flag_s[NT];
    int nb = NPTS / NT;
    int b = blockIdx.x / nb;
    int n0 = (blockIdx.x % nb) * NT;
    int tid = threadIdx.x;
    if (tid < NT) flag_s[tid] = flags[b * NPTS + n0 + tid];
    if (tid < O) {
        int g = tid / (O / 2);
        double s = st[(b * 2 + g) * 2 + 0], q = st[(b * 2 + g) * 2 + 1];
        double meand = s / M;
        double var = q / M - meand * meand;
        float mean = (float)meand;
        float rstd = (float)(1.0 / sqrt(var + 1e-5));
        float sc = rstd * gamma[tid];
        sc_s[tid] = sc;
        sh_s[tid] = beta[tid] - mean * sc;
    }
    __syncthreads();
    int o = tid % O;
    int nl0 = tid / O, nrep = 256 / O;
    float sc = sc_s[o], sh = sh_s[o];
    bool pos = (sc >= 0.f);
    for (int nl = nl0; nl < NT; nl += nrep) {
        float4 v = hilo[((long)b * NPTS + n0 + nl) * O + o];
        float h0 = pos ? fmaxf(v.x, v.z) : fminf(v.y, v.z);
        float h1 = pos ? fmaxf(v.x, v.w) : fminf(v.y, v.w);
        float v0 = h0 * sc + sh; v0 = v0 >= 0.f ? v0 : 0.2f * v0;
        float v1 = h1 * sc + sh; v1 = v1 >= 0.f ? v1 : 0.2f * v1;
        float outv = v0;
        if (flag_s[nl] && fabsf(v0 - v1) <= 0.45f) outv = 0.5f * (v0 + v1);
        smP[o * NT + nl] = v0;
        smH[o * NT + nl] = outv;
    }
    __syncthreads();
    long obase = ((long)b * 256 + coff) * NPTS + n0;
    for (int i = tid; i < O * NT; i += 256) {
        int oo = i / NT, nl = i % NT;
        featP[obase + (long)oo * NPTS + nl] = smP[i];
        featH[obase + (long)oo * NPTS + nl] = smH[i];
    }
}

// ---------------- MLP GEMM: 64o x 128n tile, 512 threads, 2x8/thread, kc=32, grid 1024 ----------------
__global__ __launch_bounds__(512) void mlp_gemm_kernel(
    const float* __restrict__ xf, const float* __restrict__ Wm, const float* __restrict__ bm,
    unsigned* __restrict__ mmax, unsigned* __restrict__ mmin, double* __restrict__ stats) {
    int b = blockIdx.z;
    int o0 = blockIdx.y * 64, n0 = blockIdx.x * 128;
    __shared__ float wm_s[64][33];    // [o][c] — reads broadcast within 16-lane groups
    __shared__ float xf_s[32][128];   // [c][n]
    int tid = threadIdx.x;
    int tx = tid & 15, ty = tid >> 4;  // tx: 8n each ; ty 0..31: 2o each
    float acc[2][8] = {};
    for (int kc = 0; kc < 256; kc += 32) {
        {
            int f = tid;                    // float4 index in 64x32 W tile (512 total)
            int o = f >> 3;                  // 8 float4 per o-row
            int c4 = (f & 7) * 4;
            float4 wv = *(const float4*)&Wm[(long)(o0 + o) * 256 + kc + c4];
            wm_s[o][c4 + 0] = wv.x;
            wm_s[o][c4 + 1] = wv.y;
            wm_s[o][c4 + 2] = wv.z;
            wm_s[o][c4 + 3] = wv.w;
        }
#pragma unroll
        for (int i = 0; i < 2; ++i) {
            int f = tid + i * 512;          // float4 index in 32x128 xf tile
            int c = f >> 5;
            int n4 = (f & 31) * 4;
            float4 v = *(const float4*)&xf[(long)b * 256 * NPTS + (long)(kc + c) * NPTS + n0 + n4];
            *(float4*)&xf_s[c][n4] = v;
        }
        __syncthreads();
        for (int c = 0; c < 32; ++c) {
            float a[2], bb[8];
            a[0] = wm_s[ty * 2 + 0][c];
            a[1] = wm_s[ty * 2 + 1][c];
            float4 bA = *(const float4*)&xf_s[c][tx * 4];
            float4 bB = *(const float4*)&xf_s[c][64 + tx * 4];
            bb[0] = bA.x; bb[1] = bA.y; bb[2] = bA.z; bb[3] = bA.w;
            bb[4] = bB.x; bb[5] = bB.y; bb[6] = bB.z; bb[7] = bB.w;
#pragma unroll
            for (int u = 0; u < 2; ++u)
#pragma unroll
                for (int v = 0; v < 8; ++v) acc[u][v] = fmaf(a[u], bb[v], acc[u][v]);
        }
        __syncthreads();
    }
    double s = 0.0, q = 0.0;
#pragma unroll
    for (int u = 0; u < 2; ++u) {
        int o = o0 + ty * 2 + u;
        float bv = bm[o];
        float mx = -3.0e38f, mn = 3.0e38f;
#pragma unroll
        for (int v = 0; v < 8; ++v) {
            float hv = acc[u][v] + bv;
            mx = fmaxf(mx, hv);
            mn = fminf(mn, hv);
            s += (double)hv;
            q += (double)hv * (double)hv;
        }
        for (int d = 1; d < 16; d <<= 1) {
            mx = fmaxf(mx, __shfl_xor(mx, d));
            mn = fminf(mn, __shfl_xor(mn, d));
        }
        if (tx == 0) {
            atomicMax(&mmax[((long)b << 10) + o], f2key(mx));
            atomicMin(&mmin[((long)b << 10) + o], f2key(mn));
        }
    }
    for (int off = 32; off > 0; off >>= 1) {
        s += __shfl_xor(s, off);
        q += __shfl_xor(q, off);
    }
    __shared__ double rs[8], rq[8];
    int wid = tid >> 6;
    if ((tid & 63) == 0) { rs[wid] = s; rq[wid] = q; }
    __syncthreads();
    if (tid == 0) {
        s = 0.0; q = 0.0;
#pragma unroll
        for (int ww = 0; ww < 8; ++ww) { s += rs[ww]; q += rq[ww]; }
        int g = o0 >> 7;
        atomicAdd(&stats[(b * 8 + g) * 2 + 0], s);
        atomicAdd(&stats[(b * 8 + g) * 2 + 1], q);
    }
}

// ---------------- MLP final: recompute ms per block + normalize + relu ----------------
__global__ void mlp_final2_kernel(
    const double* __restrict__ st, const unsigned* __restrict__ mmax,
    const unsigned* __restrict__ mmin, const float* __restrict__ gm,
    const float* __restrict__ betam, float* __restrict__ x4) {
    __shared__ double ms_s[64];
    int tid = threadIdx.x;
    if (tid < 32) {
        double s = st[tid * 2], q = st[tid * 2 + 1];
        double M = 128.0 * 2048.0;
        double mean = s / M;
        double var = q / M - mean * mean;
        ms_s[tid * 2] = mean;
        ms_s[tid * 2 + 1] = 1.0 / sqrt(var + 1e-5);
    }
    __syncthreads();
    int i = blockIdx.x * 256 + tid;
    if (i >= BATCH * 1024) return;
    int b = i >> 10, o = i & 1023;
    int g = o >> 7;
    float mean = (float)ms_s[(b * 8 + g) * 2], rstd = (float)ms_s[(b * 8 + g) * 2 + 1];
    float sc = rstd * gm[o], sh = betam[o] - mean * sc;
    float hsel = (sc >= 0.f) ? key2f(mmax[i]) : key2f(mmin[i]);
    x4[i] = fmaxf(hsel * sc + sh, 0.f);
}

template<int C, int O>
static void run_layer(const float* xin, long sb, const float* W,
                      const float* gamma, const float* beta, int coff,
                      float* featP, float* featH,
                      double* xxb, float* dist, bool full, int* idx, int* flags,
                      float* pbuf, float* rbuf, float4* hilo,
                      double* stl, hipStream_t stream) {
    xx64_kernel<<<(BATCH * NPTS + 255) / 256, 256, 0, stream>>>(xin, sb, C, xxb);
    if (full) {
        dist_kernel<<<dim3(32, 32, BATCH), 256, 0, stream>>>(xin, sb, C, xxb, dist, 0);
        topk_wave_kernel<<<dim3(NPTS / 4, 1, BATCH), 256, 0, stream>>>(dist, idx, flags, 0);
    } else {
        for (int b = 0; b < BATCH; ++b) {
            dist_kernel<<<dim3(32, 32, 1), 256, 0, stream>>>(xin, sb, C, xxb, dist, b);
            topk_wave_kernel<<<dim3(NPTS / 4, 1, 1), 256, 0, stream>>>(dist, idx, flags, b);
        }
    }
    pr_kernel<C, O><<<BATCH * NPTS / 32, 256, 0, stream>>>(xin, sb, W, pbuf, rbuf);
    gather_kernel<O, 8><<<BATCH * NPTS / 8, 256, 0, stream>>>(pbuf, rbuf, idx, hilo, stl);
    double M = (double)((long)(O / 2) * NPTS * KNN);
    finalize_kernel<O><<<BATCH * NPTS / 16, 256, 0, stream>>>(hilo, flags, stl, M,
                                                              gamma, beta, featP, featH, coff);
}

extern "C" void kernel_launch(void* const* d_in, const int* in_sizes, int n_in,
                              void* d_out, int out_size, void* d_ws, size_t ws_size,
                              hipStream_t stream) {
    const float* x = (const float*)d_in[0];
    const float* W1 = (const float*)d_in[1];
    const float* g1 = (const float*)d_in[2];
    const float* b1 = (const float*)d_in[3];
    const float* W2 = (const float*)d_in[4];
    const float* g2 = (const float*)d_in[5];
    const float* b2 = (const float*)d_in[6];
    const float* W3 = (const float*)d_in[7];
    const float* g3 = (const float*)d_in[8];
    const float* b3 = (const float*)d_in[9];
    const float* Wm = (const float*)d_in[10];
    const float* bm = (const float*)d_in[11];
    const float* gm = (const float*)d_in[12];
    const float* betam = (const float*)d_in[13];

    float* out = (float*)d_out;
    float* x4 = out;
    float* featH = out + BATCH * 1024;

    char* ws = (char*)d_ws;
    size_t off = 0;
    auto alloc = [&](size_t bytes) -> void* {
        void* pp = ws + off;
        off += (bytes + 255) & ~(size_t)255;
        return pp;
    };
    double* xxb = (double*)alloc((size_t)BATCH * NPTS * 8);
    int* idx = (int*)alloc((size_t)BATCH * NPTS * KSEL * 4);
    int* flags = (int*)alloc((size_t)BATCH * NPTS * 4);
    float* featP = (float*)alloc((size_t)BATCH * 256 * NPTS * 4);
    float* pbuf = (float*)alloc((size_t)BATCH * NPTS * 128 * 4);
    float* rbuf = (float*)alloc((size_t)BATCH * NPTS * 128 * 4);
    float4* hilo = (float4*)alloc((size_t)BATCH * NPTS * 128 * 16);
    double* statsd = (double*)alloc(128 * 8);   // layers: +0,+16,+32 ; mlp: +64
    unsigned* mmax = (unsigned*)alloc((size_t)BATCH * 1024 * 4);
    unsigned* mmin = (unsigned*)alloc((size_t)BATCH * 1024 * 4);
    size_t base = off;
    bool full = (ws_size >= base + (size_t)BATCH * NPTS * NPTS * 4);
    float* dist = (float*)alloc(full ? (size_t)BATCH * NPTS * NPTS * 4
                                     : (size_t)NPTS * NPTS * 4);

    hipMemsetAsync(statsd, 0, 128 * 8, stream);
    hipMemsetAsync(mmax, 0x00, (size_t)BATCH * 1024 * 4, stream);
    hipMemsetAsync(mmin, 0xFF, (size_t)BATCH * 1024 * 4, stream);

    run_layer<3, 64>(x, 3L * NPTS, W1, g1, b1, 0,
                     featP, featH, xxb, dist, full, idx, flags, pbuf, rbuf, hilo, statsd + 0, stream);
    run_layer<64, 64>(featP, 256L * NPTS, W2, g2, b2, 64,
                      featP, featH, xxb, dist, full, idx, flags, pbuf, rbuf, hilo, statsd + 16, stream);
    run_layer<64, 128>(featP + 64L * NPTS, 256L * NPTS, W3, g3, b3, 128,
                       featP, featH, xxb, dist, full, idx, flags, pbuf, rbuf, hilo, statsd + 32, stream);

    mlp_gemm_kernel<<<dim3(16, 16, BATCH), 512, 0, stream>>>(featH, Wm, bm, mmax, mmin, statsd + 64);
    mlp_final2_kernel<<<(BATCH * 1024 + 255) / 256, 256, 0, stream>>>(statsd + 64, mmax, mmin, gm, betam, x4);
    (void)in_sizes; (void)n_in; (void)out_size; (void)ws_size;
}

// Round 19
// 465.799 us; speedup vs baseline: 1.0305x; 1.0305x over previous
//
#include <hip/hip_runtime.h>
#include <hip/hip_bf16.h>

#define NPTS 2048
#define KNN 80
#define KSEL 81
#define BATCH 4

__device__ __forceinline__ unsigned f2key(float f) {
    unsigned u = __float_as_uint(f);
    return u ^ ((u & 0x80000000u) ? 0xFFFFFFFFu : 0x80000000u);
}
__device__ __forceinline__ float key2f(unsigned k) {
    unsigned u = (k & 0x80000000u) ? (k ^ 0x80000000u) : ~k;
    return __uint_as_float(u);
}

// ---------------- xx (fp64) ----------------
__global__ void xx64_kernel(const float* __restrict__ x, long sb, int C, double* __restrict__ xx) {
    int i = blockIdx.x * 256 + threadIdx.x;
    if (i >= BATCH * NPTS) return;
    int b = i / NPTS, n = i % NPTS;
    const float* xp = x + (long)b * sb + n;
    double s = 0.0;
    for (int c = 0; c < C; ++c) { double v = (double)xp[(long)c * NPTS]; s = fma(v, v, s); }
    xx[i] = s;
}

// ---------------- dist: fp32 accumulate, fp64 final combine -> fp32 ----------------
__global__ __launch_bounds__(256) void dist_kernel(
    const float* __restrict__ x, long sb, int C,
    const double* __restrict__ xx, float* __restrict__ dist, int b_base) {
    int bz = blockIdx.z;
    int b = b_base + bz;
    int i0 = blockIdx.y * 64, j0 = blockIdx.x * 64;
    __shared__ float xi[32][64];
    __shared__ float xj[32][64];
    const float* xb = x + (long)b * sb;
    int tid = threadIdx.x, tx = tid & 15, ty = tid >> 4;
    float acc[4][4] = {};
    for (int cc = 0; cc < C; cc += 32) {
        int Cc = C - cc; if (Cc > 32) Cc = 32;
        for (int t = tid; t < Cc * 64; t += 256) {
            int c = t >> 6, l = t & 63;
            xi[c][l] = xb[(long)(cc + c) * NPTS + i0 + l];
            xj[c][l] = xb[(long)(cc + c) * NPTS + j0 + l];
        }
        __syncthreads();
        for (int c = 0; c < Cc; ++c) {
            float a[4], bb[4];
#pragma unroll
            for (int u = 0; u < 4; ++u) a[u] = xi[c][ty * 4 + u];
#pragma unroll
            for (int v = 0; v < 4; ++v) bb[v] = xj[c][tx * 4 + v];
#pragma unroll
            for (int u = 0; u < 4; ++u)
#pragma unroll
                for (int v = 0; v < 4; ++v) acc[u][v] = fmaf(a[u], bb[v], acc[u][v]);
        }
        __syncthreads();
    }
    const double* xxb = xx + b * NPTS;
    float* drow = dist + (long)bz * NPTS * NPTS;
#pragma unroll
    for (int u = 0; u < 4; ++u) {
        int i = i0 + ty * 4 + u;
        double xxi = xxb[i];
#pragma unroll
        for (int v = 0; v < 4; ++v) {
            int j = j0 + tx * 4 + v;
            drow[(long)i * NPTS + j] = (float)(2.0 * (double)acc[u][v] - xxi - xxb[j]);
        }
    }
}

// ---------------- top-81: wave-per-row radix select, 4-copy histogram ----------------
__global__ __launch_bounds__(256) void topk_wave_kernel(
    const float* __restrict__ dist, int* __restrict__ idxout,
    int* __restrict__ flags, int b_base) {
    int bz = blockIdx.z;
    int b = b_base + bz;
    int tid = threadIdx.x;
    int lane = tid & 63, w = tid >> 6;
    int row = blockIdx.x * 4 + w;
    const float* dr = dist + ((long)bz * NPTS + row) * NPTS;

    unsigned kv[32];
#pragma unroll
    for (int i = 0; i < 8; ++i) {
        float4 a = *(const float4*)(dr + i * 256 + lane * 4);
        kv[i * 4 + 0] = f2key(a.x);
        kv[i * 4 + 1] = f2key(a.y);
        kv[i * 4 + 2] = f2key(a.z);
        kv[i * 4 + 3] = f2key(a.w);
    }

    __shared__ unsigned hist[4][256][4];   // [wave][bin][copy]
    __shared__ int sel_s[4][KSEL];
    __shared__ float selv_s[4][KSEL];

    unsigned prefix = 0;
    int rem = KSEL;
    int cp = lane & 3;

    for (int pass = 0; pass < 4; ++pass) {
        int shift = 24 - pass * 8;
        uint4* h4 = (uint4*)&hist[w][0][0];
#pragma unroll
        for (int t = 0; t < 4; ++t) h4[lane + t * 64] = make_uint4(0u, 0u, 0u, 0u);
        unsigned pm = (pass == 0) ? 0u : (0xFFFFFFFFu << (shift + 8));
#pragma unroll
        for (int u = 0; u < 32; ++u) {
            if ((kv[u] & pm) == prefix)
                atomicAdd(&hist[w][(kv[u] >> shift) & 255u][cp], 1u);
        }
        uint4 c0 = h4[lane * 4 + 0];
        uint4 c1 = h4[lane * 4 + 1];
        uint4 c2 = h4[lane * 4 + 2];
        uint4 c3 = h4[lane * 4 + 3];
        unsigned b0 = c0.x + c0.y + c0.z + c0.w;
        unsigned b1 = c1.x + c1.y + c1.z + c1.w;
        unsigned b2 = c2.x + c2.y + c2.z + c2.w;
        unsigned b3 = c3.x + c3.y + c3.z + c3.w;
        unsigned loc3 = b3, loc2 = b3 + b2, loc1 = b3 + b2 + b1, loc0 = b3 + b2 + b1 + b0;
        unsigned tot = loc0;
        unsigned suf = tot;
#pragma unroll
        for (int d = 1; d < 64; d <<= 1) {
            unsigned o = __shfl_down(suf, d);
            suf += (lane + d < 64) ? o : 0u;
        }
        unsigned after = suf - tot;
        int fdig = -1, frem = 0;
        unsigned ge, gt;
        ge = loc0 + after; gt = loc1 + after;
        if (ge >= (unsigned)rem && gt < (unsigned)rem) { fdig = lane * 4 + 0; frem = rem - (int)gt; }
        ge = loc1 + after; gt = loc2 + after;
        if (ge >= (unsigned)rem && gt < (unsigned)rem) { fdig = lane * 4 + 1; frem = rem - (int)gt; }
        ge = loc2 + after; gt = loc3 + after;
        if (ge >= (unsigned)rem && gt < (unsigned)rem) { fdig = lane * 4 + 2; frem = rem - (int)gt; }
        ge = loc3 + after; gt = after;
        if (ge >= (unsigned)rem && gt < (unsigned)rem) { fdig = lane * 4 + 3; frem = rem - (int)gt; }
        unsigned long long bal = __ballot(fdig >= 0);
        int src = __ffsll((unsigned long long)bal) - 1;
        fdig = __shfl(fdig, src);
        frem = __shfl(frem, src);
        prefix |= ((unsigned)fdig) << shift;
        rem = frem;
    }

    int myc = 0;
#pragma unroll
    for (int u = 0; u < 32; ++u) myc += (kv[u] > prefix) ? 1 : 0;
    int inc = myc;
#pragma unroll
    for (int d = 1; d < 64; d <<= 1) {
        int o = __shfl_up(inc, d);
        inc += (lane >= d) ? o : 0;
    }
    int off = inc - myc;
    int pos = off;
#pragma unroll
    for (int u = 0; u < 32; ++u) {
        if (kv[u] > prefix) {
            int e = (u >> 2) * 256 + lane * 4 + (u & 3);
            sel_s[w][pos] = e;
            selv_s[w][pos] = key2f(kv[u]);
            ++pos;
        }
    }
    int cgt = __shfl(inc, 63);

    unsigned tmask = 0;
#pragma unroll
    for (int u = 0; u < 32; ++u)
        if (kv[u] == prefix) tmask |= (1u << u);
    float vtie = key2f(prefix);
    for (int t = 0; t < rem; ++t) {
        int best = 0x7FFFFFFF;
        unsigned m = tmask;
        while (m) {
            int u = __ffs(m) - 1;
            m &= m - 1;
            int e = (u >> 2) * 256 + lane * 4 + (u & 3);
            best = min(best, e);
        }
#pragma unroll
        for (int d = 32; d > 0; d >>= 1) best = min(best, __shfl_xor(best, d));
        if (((best >> 2) & 63) == lane) {
            int u = ((best >> 8) << 2) | (best & 3);
            tmask &= ~(1u << u);
        }
        if (lane == 0) { sel_s[w][cgt + t] = best; selv_s[w][cgt + t] = vtie; }
    }

    unsigned bk = 0xFFFFFFFFu; int bi = -1, bp = -1;
    if (lane < KSEL) { bk = f2key(selv_s[w][lane]); bi = sel_s[w][lane]; bp = lane; }
    int l2 = lane + 64;
    if (l2 < KSEL) {
        unsigned k2 = f2key(selv_s[w][l2]); int i2 = sel_s[w][l2];
        if (k2 < bk || (k2 == bk && i2 > bi)) { bk = k2; bi = i2; bp = l2; }
    }
#pragma unroll
    for (int d = 32; d > 0; d >>= 1) {
        unsigned ok = __shfl_xor(bk, d);
        int oi = __shfl_xor(bi, d);
        int op = __shfl_xor(bp, d);
        if (ok < bk || (ok == bk && oi > bi)) { bk = ok; bi = oi; bp = op; }
    }
    int p81 = bp;
    bk = 0xFFFFFFFFu; bi = -1; bp = -1;
    if (lane < KSEL && lane != p81) { bk = f2key(selv_s[w][lane]); bi = sel_s[w][lane]; bp = lane; }
    if (l2 < KSEL && l2 != p81) {
        unsigned k2 = f2key(selv_s[w][l2]); int i2 = sel_s[w][l2];
        if (k2 < bk || (k2 == bk && i2 > bi)) { bk = k2; bi = i2; bp = l2; }
    }
#pragma unroll
    for (int d = 32; d > 0; d >>= 1) {
        unsigned ok = __shfl_xor(bk, d);
        int oi = __shfl_xor(bi, d);
        int op = __shfl_xor(bp, d);
        if (ok < bk || (ok == bk && oi > bi)) { bk = ok; bi = oi; bp = op; }
    }
    int p80 = bp;

    if (lane == 0) {
        int ts; float tv;
        ts = sel_s[w][80]; sel_s[w][80] = sel_s[w][p81]; sel_s[w][p81] = ts;
        tv = selv_s[w][80]; selv_s[w][80] = selv_s[w][p81]; selv_s[w][p81] = tv;
        if (p80 == 80) p80 = p81;
        ts = sel_s[w][79]; sel_s[w][79] = sel_s[w][p80]; sel_s[w][p80] = ts;
        tv = selv_s[w][79]; selv_s[w][79] = selv_s[w][p80]; selv_s[w][p80] = tv;
        float d80f = selv_s[w][79], d81f = selv_s[w][80];
        float eta = 8e-5f + 4e-6f * fabsf(d80f);
        flags[b * NPTS + row] = ((d80f - d81f) <= eta) ? 1 : 0;
    }
    int* outp = idxout + ((long)b * NPTS + row) * KSEL;
    for (int t = lane; t < KSEL; t += 64) outp[t] = sel_s[w][t];
}

// ---------------- p/r projections ----------------
template<int C, int O>
__global__ __launch_bounds__(256) void pr_kernel(
    const float* __restrict__ x, long sb, const float* __restrict__ W,
    float* __restrict__ p, float* __restrict__ r) {
    __shared__ float wp[C * O];
    __shared__ float wr[C * O];
    __shared__ float xs[C][32];
    int nb = NPTS / 32;
    int b = blockIdx.x / nb;
    int n0 = (blockIdx.x % nb) * 32;
    int tid = threadIdx.x;
    for (int t = tid; t < C * O; t += 256) {
        int o = t / C, c = t % C;
        float w1 = W[o * 2 * C + c];
        wp[o * C + c] = w1;
        wr[o * C + c] = W[o * 2 * C + C + c] - w1;
    }
    const float* xb = x + (long)b * sb;
    for (int t = tid; t < C * 32; t += 256) {
        int c = t / 32, nn = t & 31;
        xs[c][nn] = xb[(long)c * NPTS + n0 + nn];
    }
    __syncthreads();
    int o = tid % O;
    int nl0 = tid / O, per = 256 / O;
    for (int nl = nl0; nl < 32; nl += per) {
        float pa = 0.f, ra = 0.f;
        for (int c = 0; c < C; ++c) {
            float xv = xs[c][nl];
            pa = fmaf(wp[o * C + c], xv, pa);
            ra = fmaf(wr[o * C + c], xv, ra);
        }
        long po = ((long)b * NPTS + n0 + nl) * O + o;
        p[po] = pa;
        r[po] = ra;
    }
}

// ---------------- FUSED gather: hilo + fp64 stats via global atomics ----------------
template<int O, int NT>
__global__ __launch_bounds__(256) void gather_kernel(
    const float* __restrict__ p, const float* __restrict__ r,
    const int* __restrict__ idx, float4* __restrict__ hilo,
    double* __restrict__ stats) {
    const int R = (NT * O) / 256;
    const int STEP = 256 / O;
    __shared__ float r_s[NT * O];
    __shared__ int idx_s[NT * KSEL];
    __shared__ double gs8[8], gq8[8];
    int nb = NPTS / NT;
    int b = blockIdx.x / nb;
    int n0 = (blockIdx.x % nb) * NT;
    int tid = threadIdx.x;
    for (int t = tid; t < NT * O; t += 256) r_s[t] = r[((long)b * NPTS + n0) * O + t];
    for (int t = tid; t < NT * KSEL; t += 256) idx_s[t] = idx[((long)b * NPTS + n0) * KSEL + t];
    __syncthreads();
    int o = tid % O;
    int nlb = tid / O;
    const float* pb = p + (long)b * NPTS * O;
    float hi[R], lo[R], ha[R], hb[R], rv[R];
    int nlr[R];
#pragma unroll
    for (int u = 0; u < R; ++u) {
        nlr[u] = nlb + u * STEP;
        rv[u] = r_s[nlr[u] * O + o];
        hi[u] = -3.0e38f; lo[u] = 3.0e38f;
    }
    float s0 = 0.f, s1 = 0.f, q0 = 0.f, q1 = 0.f;
    int kk = 0;
    for (; kk + 3 < KNN - 1; kk += 4) {
        int j0[R], j1[R], j2[R], j3[R];
#pragma unroll
        for (int u = 0; u < R; ++u) {
            const int* ip = &idx_s[nlr[u] * KSEL + kk];
            j0[u] = ip[0]; j1[u] = ip[1]; j2[u] = ip[2]; j3[u] = ip[3];
        }
#pragma unroll
        for (int u = 0; u < R; ++u) {
            float h0 = pb[(long)j0[u] * O + o] + rv[u];
            float h1 = pb[(long)j1[u] * O + o] + rv[u];
            float h2 = pb[(long)j2[u] * O + o] + rv[u];
            float h3 = pb[(long)j3[u] * O + o] + rv[u];
            hi[u] = fmaxf(hi[u], fmaxf(fmaxf(h0, h1), fmaxf(h2, h3)));
            lo[u] = fminf(lo[u], fminf(fminf(h0, h1), fminf(h2, h3)));
            s0 += h0 + h2;
            s1 += h1 + h3;
            q0 = fmaf(h0, h0, q0); q0 = fmaf(h2, h2, q0);
            q1 = fmaf(h1, h1, q1); q1 = fmaf(h3, h3, q1);
        }
    }
    for (; kk < KNN - 1; ++kk) {
#pragma unroll
        for (int u = 0; u < R; ++u) {
            int j = idx_s[nlr[u] * KSEL + kk];
            float h = pb[(long)j * O + o] + rv[u];
            hi[u] = fmaxf(hi[u], h);
            lo[u] = fminf(lo[u], h);
            s0 += h;
            q0 = fmaf(h, h, q0);
        }
    }
#pragma unroll
    for (int u = 0; u < R; ++u) {
        int j = idx_s[nlr[u] * KSEL + (KNN - 1)];
        ha[u] = pb[(long)j * O + o] + rv[u];
        s0 += ha[u];
        q0 = fmaf(ha[u], ha[u], q0);
        int j2 = idx_s[nlr[u] * KSEL + KNN];
        hb[u] = pb[(long)j2 * O + o] + rv[u];
    }
#pragma unroll
    for (int u = 0; u < R; ++u)
        hilo[((long)b * NPTS + n0 + nlr[u]) * O + o] = make_float4(hi[u], lo[u], ha[u], hb[u]);
    double s = (double)s0 + (double)s1;
    double q = (double)q0 + (double)q1;
    for (int off = 16; off > 0; off >>= 1) {
        s += __shfl_xor(s, off);
        q += __shfl_xor(q, off);
    }
    int hw = tid >> 5;
    if ((tid & 31) == 0) { gs8[hw] = s; gq8[hw] = q; }
    __syncthreads();
    if (tid < 2) {
        double ss = 0.0, qq = 0.0;
        for (int h2 = 0; h2 < 8; ++h2) {
            int o0 = (h2 * 32) % O;
            int g = o0 / (O / 2);
            if (g == tid) { ss += gs8[h2]; qq += gq8[h2]; }
        }
        atomicAdd(&stats[(b * 2 + tid) * 2 + 0], ss);
        atomicAdd(&stats[(b * 2 + tid) * 2 + 1], qq);
    }
}

// ---------------- finalize: compute ms from stats + normalize extremes + leaky + hedge ----------------
template<int O>
__global__ __launch_bounds__(256) void finalize_kernel(
    const float4* __restrict__ hilo, const int* __restrict__ flags,
    const double* __restrict__ st, double M,
    const float* __restrict__ gamma, const float* __restrict__ beta,
    float* __restrict__ featP, float* __restrict__ featH, int coff) {
    const int NT = 16;
    __shared__ float smP[O * NT], smH[O * NT];
    __shared__ float sc_s[O], sh_s[O];
    __shared__ int flag_s[NT];
    int nb = NPTS / NT;
    int b = blockIdx.x / nb;
    int n0 = (blockIdx.x % nb) * NT;
    int tid = threadIdx.x;
    if (tid < NT) flag_s[tid] = flags[b * NPTS + n0 + tid];
    if (tid < O) {
        int g = tid / (O / 2);
        double s = st[(b * 2 + g) * 2 + 0], q = st[(b * 2 + g) * 2 + 1];
        double meand = s / M;
        double var = q / M - meand * meand;
        float mean = (float)meand;
        float rstd = (float)(1.0 / sqrt(var + 1e-5));
        float sc = rstd * gamma[tid];
        sc_s[tid] = sc;
        sh_s[tid] = beta[tid] - mean * sc;
    }
    __syncthreads();
    int o = tid % O;
    int nl0 = tid / O, nrep = 256 / O;
    float sc = sc_s[o], sh = sh_s[o];
    bool pos = (sc >= 0.f);
    for (int nl = nl0; nl < NT; nl += nrep) {
        float4 v = hilo[((long)b * NPTS + n0 + nl) * O + o];
        float h0 = pos ? fmaxf(v.x, v.z) : fminf(v.y, v.z);
        float h1 = pos ? fmaxf(v.x, v.w) : fminf(v.y, v.w);
        float v0 = h0 * sc + sh; v0 = v0 >= 0.f ? v0 : 0.2f * v0;
        float v1 = h1 * sc + sh; v1 = v1 >= 0.f ? v1 : 0.2f * v1;
        float outv = v0;
        if (flag_s[nl] && fabsf(v0 - v1) <= 0.45f) outv = 0.5f * (v0 + v1);
        smP[o * NT + nl] = v0;
        smH[o * NT + nl] = outv;
    }
    __syncthreads();
    long obase = ((long)b * 256 + coff) * NPTS + n0;
    for (int i = tid; i < O * NT; i += 256) {
        int oo = i / NT, nl = i % NT;
        featP[obase + (long)oo * NPTS + nl] = smP[i];
        featH[obase + (long)oo * NPTS + nl] = smH[i];
    }
}

// ---------------- MLP GEMM: 128o x 128n tile, 512 threads, 4x8/thread, kc=32 (33KB LDS) ----------------
__global__ __launch_bounds__(512) void mlp_gemm_kernel(
    const float* __restrict__ xf, const float* __restrict__ Wm, const float* __restrict__ bm,
    unsigned* __restrict__ mmax, unsigned* __restrict__ mmin, double* __restrict__ stats) {
    int b = blockIdx.z;
    int o0 = blockIdx.y * 128, n0 = blockIdx.x * 128;
    __shared__ float wm_s[128][33];   // [o][c] — reads broadcast within 16-lane groups
    __shared__ float xf_s[32][128];   // [c][n]
    int tid = threadIdx.x;
    int tx = tid & 15, ty = tid >> 4;
    float acc[4][8] = {};
    for (int kc = 0; kc < 256; kc += 32) {
#pragma unroll
        for (int i = 0; i < 2; ++i) {
            int f = tid + i * 512;          // float4 index in 128x32 W tile
            int o = f >> 3;                  // 8 float4 per o-row
            int c4 = (f & 7) * 4;
            float4 wv = *(const float4*)&Wm[(long)(o0 + o) * 256 + kc + c4];
            wm_s[o][c4 + 0] = wv.x;
            wm_s[o][c4 + 1] = wv.y;
            wm_s[o][c4 + 2] = wv.z;
            wm_s[o][c4 + 3] = wv.w;
        }
#pragma unroll
        for (int i = 0; i < 2; ++i) {
            int f = tid + i * 512;          // float4 index in 32x128 xf tile
            int c = f >> 5;
            int n4 = (f & 31) * 4;
            float4 v = *(const float4*)&xf[(long)b * 256 * NPTS + (long)(kc + c) * NPTS + n0 + n4];
            *(float4*)&xf_s[c][n4] = v;
        }
        __syncthreads();
        for (int c = 0; c < 32; ++c) {
            float a[4], bb[8];
#pragma unroll
            for (int u = 0; u < 4; ++u) a[u] = wm_s[ty * 4 + u][c];
            float4 bA = *(const float4*)&xf_s[c][tx * 4];
            float4 bB = *(const float4*)&xf_s[c][64 + tx * 4];
            bb[0] = bA.x; bb[1] = bA.y; bb[2] = bA.z; bb[3] = bA.w;
            bb[4] = bB.x; bb[5] = bB.y; bb[6] = bB.z; bb[7] = bB.w;
#pragma unroll
            for (int u = 0; u < 4; ++u)
#pragma unroll
                for (int v = 0; v < 8; ++v) acc[u][v] = fmaf(a[u], bb[v], acc[u][v]);
        }
        __syncthreads();
    }
    double s = 0.0, q = 0.0;
#pragma unroll
    for (int u = 0; u < 4; ++u) {
        int o = o0 + ty * 4 + u;
        float bv = bm[o];
        float mx = -3.0e38f, mn = 3.0e38f;
#pragma unroll
        for (int v = 0; v < 8; ++v) {
            float hv = acc[u][v] + bv;
            mx = fmaxf(mx, hv);
            mn = fminf(mn, hv);
            s += (double)hv;
            q += (double)hv * (double)hv;
        }
        for (int d = 1; d < 16; d <<= 1) {
            mx = fmaxf(mx, __shfl_xor(mx, d));
            mn = fminf(mn, __shfl_xor(mn, d));
        }
        if (tx == 0) {
            atomicMax(&mmax[((long)b << 10) + o], f2key(mx));
            atomicMin(&mmin[((long)b << 10) + o], f2key(mn));
        }
    }
    for (int off = 32; off > 0; off >>= 1) {
        s += __shfl_xor(s, off);
        q += __shfl_xor(q, off);
    }
    __shared__ double rs[8], rq[8];
    int wid = tid >> 6;
    if ((tid & 63) == 0) { rs[wid] = s; rq[wid] = q; }
    __syncthreads();
    if (tid == 0) {
        s = 0.0; q = 0.0;
#pragma unroll
        for (int ww = 0; ww < 8; ++ww) { s += rs[ww]; q += rq[ww]; }
        int g = o0 >> 7;
        atomicAdd(&stats[(b * 8 + g) * 2 + 0], s);
        atomicAdd(&stats[(b * 8 + g) * 2 + 1], q);
    }
}

// ---------------- MLP final: recompute ms per block + normalize + relu ----------------
__global__ void mlp_final2_kernel(
    const double* __restrict__ st, const unsigned* __restrict__ mmax,
    const unsigned* __restrict__ mmin, const float* __restrict__ gm,
    const float* __restrict__ betam, float* __restrict__ x4) {
    __shared__ double ms_s[64];
    int tid = threadIdx.x;
    if (tid < 32) {
        double s = st[tid * 2], q = st[tid * 2 + 1];
        double M = 128.0 * 2048.0;
        double mean = s / M;
        double var = q / M - mean * mean;
        ms_s[tid * 2] = mean;
        ms_s[tid * 2 + 1] = 1.0 / sqrt(var + 1e-5);
    }
    __syncthreads();
    int i = blockIdx.x * 256 + tid;
    if (i >= BATCH * 1024) return;
    int b = i >> 10, o = i & 1023;
    int g = o >> 7;
    float mean = (float)ms_s[(b * 8 + g) * 2], rstd = (float)ms_s[(b * 8 + g) * 2 + 1];
    float sc = rstd * gm[o], sh = betam[o] - mean * sc;
    float hsel = (sc >= 0.f) ? key2f(mmax[i]) : key2f(mmin[i]);
    x4[i] = fmaxf(hsel * sc + sh, 0.f);
}

template<int C, int O>
static void run_layer(const float* xin, long sb, const float* W,
                      const float* gamma, const float* beta, int coff,
                      float* featP, float* featH,
                      double* xxb, float* dist, bool full, int* idx, int* flags,
                      float* pbuf, float* rbuf, float4* hilo,
                      double* stl, hipStream_t stream) {
    xx64_kernel<<<(BATCH * NPTS + 255) / 256, 256, 0, stream>>>(xin, sb, C, xxb);
    if (full) {
        dist_kernel<<<dim3(32, 32, BATCH), 256, 0, stream>>>(xin, sb, C, xxb, dist, 0);
        topk_wave_kernel<<<dim3(NPTS / 4, 1, BATCH), 256, 0, stream>>>(dist, idx, flags, 0);
    } else {
        for (int b = 0; b < BATCH; ++b) {
            dist_kernel<<<dim3(32, 32, 1), 256, 0, stream>>>(xin, sb, C, xxb, dist, b);
            topk_wave_kernel<<<dim3(NPTS / 4, 1, 1), 256, 0, stream>>>(dist, idx, flags, b);
        }
    }
    pr_kernel<C, O><<<BATCH * NPTS / 32, 256, 0, stream>>>(xin, sb, W, pbuf, rbuf);
    gather_kernel<O, 8><<<BATCH * NPTS / 8, 256, 0, stream>>>(pbuf, rbuf, idx, hilo, stl);
    double M = (double)((long)(O / 2) * NPTS * KNN);
    finalize_kernel<O><<<BATCH * NPTS / 16, 256, 0, stream>>>(hilo, flags, stl, M,
                                                              gamma, beta, featP, featH, coff);
}

extern "C" void kernel_launch(void* const* d_in, const int* in_sizes, int n_in,
                              void* d_out, int out_size, void* d_ws, size_t ws_size,
                              hipStream_t stream) {
    const float* x = (const float*)d_in[0];
    const float* W1 = (const float*)d_in[1];
    const float* g1 = (const float*)d_in[2];
    const float* b1 = (const float*)d_in[3];
    const float* W2 = (const float*)d_in[4];
    const float* g2 = (const float*)d_in[5];
    const float* b2 = (const float*)d_in[6];
    const float* W3 = (const float*)d_in[7];
    const float* g3 = (const float*)d_in[8];
    const float* b3 = (const float*)d_in[9];
    const float* Wm = (const float*)d_in[10];
    const float* bm = (const float*)d_in[11];
    const float* gm = (const float*)d_in[12];
    const float* betam = (const float*)d_in[13];

    float* out = (float*)d_out;
    float* x4 = out;
    float* featH = out + BATCH * 1024;

    char* ws = (char*)d_ws;
    size_t off = 0;
    auto alloc = [&](size_t bytes) -> void* {
        void* pp = ws + off;
        off += (bytes + 255) & ~(size_t)255;
        return pp;
    };
    double* xxb = (double*)alloc((size_t)BATCH * NPTS * 8);
    int* idx = (int*)alloc((size_t)BATCH * NPTS * KSEL * 4);
    int* flags = (int*)alloc((size_t)BATCH * NPTS * 4);
    float* featP = (float*)alloc((size_t)BATCH * 256 * NPTS * 4);
    float* pbuf = (float*)alloc((size_t)BATCH * NPTS * 128 * 4);
    float* rbuf = (float*)alloc((size_t)BATCH * NPTS * 128 * 4);
    float4* hilo = (float4*)alloc((size_t)BATCH * NPTS * 128 * 16);
    double* statsd = (double*)alloc(128 * 8);   // layers: +0,+16,+32 ; mlp: +64
    unsigned* mmax = (unsigned*)alloc((size_t)BATCH * 1024 * 4);
    unsigned* mmin = (unsigned*)alloc((size_t)BATCH * 1024 * 4);
    size_t base = off;
    bool full = (ws_size >= base + (size_t)BATCH * NPTS * NPTS * 4);
    float* dist = (float*)alloc(full ? (size_t)BATCH * NPTS * NPTS * 4
                                     : (size_t)NPTS * NPTS * 4);

    hipMemsetAsync(statsd, 0, 128 * 8, stream);
    hipMemsetAsync(mmax, 0x00, (size_t)BATCH * 1024 * 4, stream);
    hipMemsetAsync(mmin, 0xFF, (size_t)BATCH * 1024 * 4, stream);

    run_layer<3, 64>(x, 3L * NPTS, W1, g1, b1, 0,
                     featP, featH, xxb, dist, full, idx, flags, pbuf, rbuf, hilo, statsd + 0, stream);
    run_layer<64, 64>(featP, 256L * NPTS, W2, g2, b2, 64,
                      featP, featH, xxb, dist, full, idx, flags, pbuf, rbuf, hilo, statsd + 16, stream);
    run_layer<64, 128>(featP + 64L * NPTS, 256L * NPTS, W3, g3, b3, 128,
                       featP, featH, xxb, dist, full, idx, flags, pbuf, rbuf, hilo, statsd + 32, stream);

    mlp_gemm_kernel<<<dim3(16, 8, BATCH), 512, 0, stream>>>(featH, Wm, bm, mmax, mmin, statsd + 64);
    mlp_final2_kernel<<<(BATCH * 1024 + 255) / 256, 256, 0, stream>>>(statsd + 64, mmax, mmin, gm, betam, x4);
    (void)in_sizes; (void)n_in; (void)out_size; (void)ws_size;
}